// Round 1
// baseline (90475.604 us; speedup 1.0000x reference)
//
#include <hip/hip_runtime.h>
#include <hip/hip_cooperative_groups.h>
#include <math.h>

namespace cg = cooperative_groups;

#define NBLK 256
#define NTHR 1024

// Problem sizes
constexpr int Bc = 32, Tc = 128, Ec = 512, Hc = 1024, Ac = 1024, Vc = 32000, Sc = 100;
constexpr long long OUT_ATTN = (long long)Sc * Bc * Vc; // 102,400,000 floats (preds), then attn weights

// ---- workspace layout (in floats) ----
constexpr long long O_ENCWIH = 0;                                        // [512][3072]  enc_Wih^T
constexpr long long O_ENCWHH = O_ENCWIH + (long long)512 * 3072;         // [1024][3072] enc_Whh^T
constexpr long long O_DECWIH = O_ENCWHH + (long long)1024 * 3072;        // [1536][3072] dec_Wih^T
constexpr long long O_DECWHH = O_DECWIH + (long long)1536 * 3072;        // [1024][3072] dec_Whh^T
constexpr long long O_ATTNWT = O_DECWHH + (long long)1024 * 3072;        // [2048][1024] attn_W^T
constexpr long long O_CLSWT  = O_ATTNWT + (long long)2048 * 1024;        // [1024][32000] cls_W^T
constexpr long long O_XENCT  = O_CLSWT + (long long)1024 * 32000;        // [128][512][32] emb(inputs)^T
constexpr long long O_GI     = O_XENCT + (long long)128 * 512 * 32;      // [128][32][3072] Gi (incl bih)
constexpr long long O_ENCOUT = O_GI + (long long)128 * 32 * 3072;        // [32][128][1024]
constexpr long long O_H0     = O_ENCOUT + (long long)32 * 128 * 1024;    // [1024][32] h ping
constexpr long long O_H1     = O_H0 + 32768;                             // [1024][32] h pong
constexpr long long O_AVT    = O_H1 + 32768;                             // [1024][32] av^T
constexpr long long O_CTXT   = O_AVT + 32768;                            // [1024][32] context^T
constexpr long long O_PADEC  = O_CTXT + 32768;                           // [10][32][4096] dec GRU partials
constexpr long long O_PAENC  = O_PADEC + (long long)10 * 32 * 4096;      // [8][32][3072] enc GRU partials
constexpr long long O_PAC    = O_PAENC + (long long)8 * 32 * 3072;       // [16][32][1024] av partials
constexpr long long O_PARGV  = O_PAC + (long long)16 * 32 * 1024;        // [250][32] argmax partial vals
constexpr long long O_PARGI  = O_PARGV + 8000;                           // [250][32] argmax partial idx (int)
constexpr long long O_CTR    = O_PARGI + 8000;                           // int[64] counters
constexpr long long WS_FLOATS = O_CTR + 64;                              // ~69.1M floats = ~276 MB

__global__ __launch_bounds__(NTHR, 4) void seq2seq_kernel(
    const int* __restrict__ inp, const float* __restrict__ encEmb,
    const float* __restrict__ encWih, const float* __restrict__ encWhh,
    const float* __restrict__ encBih, const float* __restrict__ encBhh,
    const float* __restrict__ decEmb, const float* __restrict__ decWih,
    const float* __restrict__ decWhh, const float* __restrict__ decBih,
    const float* __restrict__ decBhh, const float* __restrict__ attnW,
    const float* __restrict__ attnB, const float* __restrict__ clsW,
    const float* __restrict__ clsB, float* __restrict__ out,
    float* __restrict__ ws)
{
  cg::grid_group grid = cg::this_grid();
  const int bid = blockIdx.x, tid = threadIdx.x;
  const long long gtid = (long long)bid * NTHR + tid;

  __shared__ float smem[10624]; // 42.5 KB union across phases

  // ======================= P0: transposes + gathers + zeros =======================
  {
    const int sg = tid >> 8, st = tid & 255;
    float* tile = smem + sg * 1056; // 32x33
    const int c = st & 31, rr = st >> 5; // c: col-in-tile / row idx (store), rr: row-group
    for (int it = 0; it < 46; ++it) {
      int job = it * (NBLK * 4) + bid * 4 + sg;
      const float* src = nullptr; float* dst = nullptr;
      int R = 0, C = 0, tr = 0, tcd = 0;
      bool valid = true;
      int j = job;
      if (j < 1536)               { src = encWih; dst = ws + O_ENCWIH; R = 3072;  C = 512;  tr = j >> 4; tcd = j & 15; }
      else if ((j -= 1536) < 3072){ src = encWhh; dst = ws + O_ENCWHH; R = 3072;  C = 1024; tr = j >> 5; tcd = j & 31; }
      else if ((j -= 3072) < 4608){ src = decWih; dst = ws + O_DECWIH; R = 3072;  C = 1536; tr = j / 48; tcd = j % 48; }
      else if ((j -= 4608) < 3072){ src = decWhh; dst = ws + O_DECWHH; R = 3072;  C = 1024; tr = j >> 5; tcd = j & 31; }
      else if ((j -= 3072) < 2048){ src = attnW;  dst = ws + O_ATTNWT; R = 1024;  C = 2048; tr = j >> 6; tcd = j & 63; }
      else if ((j -= 2048) < 32000){src = clsW;   dst = ws + O_CLSWT;  R = 32000; C = 1024; tr = j >> 5; tcd = j & 31; }
      else valid = false;
      if (valid) {
        #pragma unroll
        for (int i = 0; i < 4; ++i) {
          int r = rr + (i << 3);
          tile[r * 33 + c] = src[(long long)(tr * 32 + r) * C + tcd * 32 + c];
        }
      }
      __syncthreads();
      if (valid) {
        #pragma unroll
        for (int i = 0; i < 4; ++i) {
          int c2 = rr + (i << 3);
          dst[(long long)(tcd * 32 + c2) * R + tr * 32 + c] = tile[c * 33 + c2];
        }
      }
      __syncthreads();
    }
  }
  // XencT[t][k][b] = enc_emb[inputs[b][t]][k]
  for (long long i = gtid; i < (long long)128 * 512 * 32; i += (long long)NBLK * NTHR) {
    int b = (int)(i & 31);
    int k = (int)((i >> 5) & 511);
    int t = (int)(i >> 14);
    int row = inp[b * Tc + t];
    ws[O_XENCT + i] = encEmb[(long long)row * Ec + k];
  }
  for (long long i = gtid; i < 32768; i += (long long)NBLK * NTHR) {
    ws[O_H0 + i] = 0.f;   // h0 = 0
    ws[O_AVT + i] = 0.f;  // attn_vec(step0) = 0
  }
  if (gtid < 64) ((int*)(ws + O_CTR))[gtid] = 0;
  grid.sync();

  // ======================= P1: Gi = emb(inputs) @ encWih^T + bih =======================
  for (int it = 0; it < 6; ++it) {
    int job = it * NBLK + bid;           // 1536 jobs: 128 t x 12 jc(256 j)
    int t = job / 12, jc = job % 12;
    int jl = tid & 255, bq = tid >> 8;   // bq: 4 groups of 8 b
    int j = jc * 256 + jl;
    float acc[8] = {0,0,0,0,0,0,0,0};
    const float* xb = ws + O_XENCT + (long long)t * 512 * 32 + bq * 8;
    const float* wb = ws + O_ENCWIH + j;
    for (int k = 0; k < 512; ++k) {
      float w = wb[(long long)k * 3072];
      float4 x0 = *(const float4*)(xb + k * 32);
      float4 x1 = *(const float4*)(xb + k * 32 + 4);
      acc[0] += x0.x * w; acc[1] += x0.y * w; acc[2] += x0.z * w; acc[3] += x0.w * w;
      acc[4] += x1.x * w; acc[5] += x1.y * w; acc[6] += x1.z * w; acc[7] += x1.w * w;
    }
    float bias = encBih[j];
    #pragma unroll
    for (int i = 0; i < 8; ++i) {
      int b = bq * 8 + i;
      ws[O_GI + ((long long)t * 32 + b) * 3072 + j] = acc[i] + bias;
    }
  }
  grid.sync();

  // ======================= P2: encoder GRU, 128 sequential steps =======================
  int par = 0; // h read buffer parity
  for (int t = 0; t < Tc; ++t) {
    if (bid < 192) { // 3 gates x 8 jc(128 j) x 8 kp(128 k)
      int g = bid / 64, rem = bid % 64;
      int jc = rem >> 3, kp = rem & 7;
      int jl = tid & 127, bq = tid >> 7; // bq: 8 groups of 4 b
      int col = g * 1024 + jc * 128 + jl;
      int b0 = bq * 4;
      float acc[4] = {0,0,0,0};
      const float* hb = ws + (par ? O_H1 : O_H0) + kp * 128 * 32 + b0;
      const float* wb = ws + O_ENCWHH + (long long)(kp * 128) * 3072 + col;
      for (int k = 0; k < 128; ++k) {
        float w = wb[(long long)k * 3072];
        float4 x = *(const float4*)(hb + k * 32);
        acc[0] += x.x * w; acc[1] += x.y * w; acc[2] += x.z * w; acc[3] += x.w * w;
      }
      #pragma unroll
      for (int i = 0; i < 4; ++i)
        ws[O_PAENC + ((long long)(kp * 32) + b0 + i) * 3072 + col] = acc[i];
      __threadfence();
      int* flag = (int*)(smem + 10600);
      if (tid == 0) {
        int old = atomicAdd((int*)(ws + O_CTR) + jc, 1);
        *flag = (old == 23) ? 1 : 0;
      }
      __syncthreads();
      if (*flag) { // last of 24 contributors for this jc: finalize gates
        __threadfence();
        int fj = tid & 127, fq = tid >> 7;
        int j = jc * 128 + fj;
        #pragma unroll
        for (int i = 0; i < 4; ++i) {
          int b = fq * 4 + i;
          float gr = 0, gz = 0, gn = 0;
          #pragma unroll
          for (int kp2 = 0; kp2 < 8; ++kp2) {
            long long base = O_PAENC + ((long long)(kp2 * 32) + b) * 3072;
            gr += ws[base + j];
            gz += ws[base + 1024 + j];
            gn += ws[base + 2048 + j];
          }
          long long gib = O_GI + ((long long)t * 32 + b) * 3072;
          float gir = ws[gib + j], giz = ws[gib + 1024 + j], gin = ws[gib + 2048 + j];
          float r = 1.f / (1.f + expf(-(gir + gr + encBhh[j])));
          float z = 1.f / (1.f + expf(-(giz + gz + encBhh[1024 + j])));
          float n = tanhf(gin + r * (gn + encBhh[2048 + j]));
          float hold = ws[(par ? O_H1 : O_H0) + (long long)j * 32 + b];
          float hn = (1.f - z) * n + z * hold;
          ws[(par ? O_H0 : O_H1) + (long long)j * 32 + b] = hn;
          ws[O_ENCOUT + ((long long)b * 128 + t) * 1024 + j] = hn;
        }
        if (tid == 0) atomicSub((int*)(ws + O_CTR) + jc, 24);
      }
    }
    grid.sync();
    par ^= 1;
  }
  // par == 0 here; h_enc is in H0.

  // ======================= P3: decoder, 100 sequential steps =======================
  for (int s = 0; s < Sc; ++s) {
    int* nids = (int*)(smem + 10368); // [32]
    // ---- A: token ids (argmax reduce) + GRU partial GEMM ----
    {
      if (s == 0) {
        if (tid < 32) nids[tid] = 0;
      } else {
        float* pv = smem;               // [32 chunks][32 b]
        int*   pi = (int*)(smem + 1024);
        int b = tid & 31, ch = tid >> 5;
        float bv = -3.4e38f; int bi = 0;
        for (int r = ch * 8; r < ch * 8 + 8 && r < 250; ++r) {
          float v = ws[O_PARGV + r * 32 + b];
          int ix = ((int*)(ws + O_PARGI))[r * 32 + b];
          if (v > bv || (v == bv && ix < bi)) { bv = v; bi = ix; }
        }
        pv[ch * 32 + b] = bv; pi[ch * 32 + b] = bi;
        __syncthreads();
        if (tid < 32) {
          float bb = -3.4e38f; int bbi = 0;
          for (int c2 = 0; c2 < 32; ++c2) {
            float v = pv[c2 * 32 + tid]; int ix = pi[c2 * 32 + tid];
            if (v > bb || (v == bb && ix < bbi)) { bb = v; bbi = ix; }
          }
          nids[tid] = bbi;
        }
      }
      __syncthreads();
      if (bid < 240) {
        // gates: 0=r (kp<10), 1=z (kp<10), 2=gi_n (kp<6, k<1536), 3=gh_n (kp<4, k>=1536)
        int gate, loc;
        if (bid < 80)       { gate = 0; loc = bid; }
        else if (bid < 160) { gate = 1; loc = bid - 80; }
        else if (bid < 208) { gate = 2; loc = bid - 160; }
        else                { gate = 3; loc = bid - 208; }
        int nkp = (gate < 2) ? 10 : ((gate == 2) ? 6 : 4);
        int jc = loc / nkp, kp = loc % nkp;
        int jl = tid & 127, bq = tid >> 7;
        int b0 = bq * 4;
        int jcol = jc * 128 + jl;
        int kg = (gate == 3 ? 1536 : 0) + kp * 256; // k start in x=[emb512|av1024|h1024]
        int wcol = (gate >= 2 ? 2048 : gate * 1024) + jcol;
        const float* wb = (kg < 1536) ? (ws + O_DECWIH + (long long)kg * 3072 + wcol)
                                      : (ws + O_DECWHH + (long long)(kg - 1536) * 3072 + wcol);
        float acc[4] = {0,0,0,0};
        if (kg < 512) {
          const float* e0 = decEmb + (long long)nids[b0    ] * 512 + kg;
          const float* e1 = decEmb + (long long)nids[b0 + 1] * 512 + kg;
          const float* e2 = decEmb + (long long)nids[b0 + 2] * 512 + kg;
          const float* e3 = decEmb + (long long)nids[b0 + 3] * 512 + kg;
          for (int k = 0; k < 256; ++k) {
            float w = wb[(long long)k * 3072];
            acc[0] += e0[k] * w; acc[1] += e1[k] * w; acc[2] += e2[k] * w; acc[3] += e3[k] * w;
          }
        } else {
          const float* xb = (kg < 1536) ? (ws + O_AVT + (long long)(kg - 512) * 32 + b0)
                                        : (ws + (par ? O_H1 : O_H0) + (long long)(kg - 1536) * 32 + b0);
          for (int k = 0; k < 256; ++k) {
            float w = wb[(long long)k * 3072];
            float4 x = *(const float4*)(xb + k * 32);
            acc[0] += x.x * w; acc[1] += x.y * w; acc[2] += x.z * w; acc[3] += x.w * w;
          }
        }
        int colout = gate * 1024 + jcol;
        #pragma unroll
        for (int i = 0; i < 4; ++i)
          ws[O_PADEC + ((long long)(kp * 32) + b0 + i) * 4096 + colout] = acc[i];
      }
    }
    grid.sync();

    // ---- B: per-b gates finalize + attention (scores/softmax/context) ----
    if (bid < 32) {
      int b = bid;
      float* h2l = smem;          // [1024]
      float* scl = smem + 1024;   // [128]
      float* wl  = smem + 1152;   // [128]
      float* red = smem + 1280;   // [4]
      {
        int j = tid;
        float gr = 0, gz = 0, gin = 0, ghn = 0;
        #pragma unroll
        for (int kp = 0; kp < 10; ++kp) {
          long long base = O_PADEC + ((long long)(kp * 32) + b) * 4096;
          gr += ws[base + j];
          gz += ws[base + 1024 + j];
          if (kp < 6) gin += ws[base + 2048 + j];
          if (kp < 4) ghn += ws[base + 3072 + j];
        }
        float r = 1.f / (1.f + expf(-(gr + decBih[j] + decBhh[j])));
        float z = 1.f / (1.f + expf(-(gz + decBih[1024 + j] + decBhh[1024 + j])));
        float n = tanhf(gin + decBih[2048 + j] + r * (ghn + decBhh[2048 + j]));
        float hold = ws[(par ? O_H1 : O_H0) + (long long)j * 32 + b];
        float h2 = (1.f - z) * n + z * hold;
        ws[(par ? O_H0 : O_H1) + (long long)j * 32 + b] = h2;
        h2l[j] = h2;
      }
      __syncthreads();
      { // scores: wave per t-octave
        int wv = tid >> 6, lane = tid & 63;
        float h2v[16];
        #pragma unroll
        for (int i = 0; i < 16; ++i) h2v[i] = h2l[lane + (i << 6)];
        for (int t8 = 0; t8 < 8; ++t8) {
          int tt = wv * 8 + t8;
          const float* eo = ws + O_ENCOUT + ((long long)b * 128 + tt) * 1024 + lane;
          float a = 0;
          #pragma unroll
          for (int i = 0; i < 16; ++i) a += eo[i << 6] * h2v[i];
          #pragma unroll
          for (int off = 32; off; off >>= 1) a += __shfl_xor(a, off, 64);
          if (lane == 0) scl[tt] = a;
        }
      }
      __syncthreads();
      { // softmax over 128
        float v = 0, m = -3.4e38f;
        if (tid < 128) {
          v = scl[tid]; m = v;
          #pragma unroll
          for (int off = 32; off; off >>= 1) m = fmaxf(m, __shfl_xor(m, off, 64));
          if ((tid & 63) == 0) red[tid >> 6] = m;
        }
        __syncthreads();
        float mm = fmaxf(red[0], red[1]);
        float e = 0.f;
        if (tid < 128) {
          e = expf(v - mm);
          float se = e;
          #pragma unroll
          for (int off = 32; off; off >>= 1) se += __shfl_xor(se, off, 64);
          if ((tid & 63) == 0) red[2 + (tid >> 6)] = se;
        }
        __syncthreads();
        if (tid < 128) {
          float wgt = e / (red[2] + red[3]);
          wl[tid] = wgt;
          out[OUT_ATTN + ((long long)s * 32 + b) * 128 + tid] = wgt;
        }
      }
      __syncthreads();
      { // context
        int j = tid;
        float a = 0;
        const float* eo = ws + O_ENCOUT + (long long)b * 128 * 1024 + j;
        for (int tt = 0; tt < 128; ++tt) a += wl[tt] * eo[(long long)tt * 1024];
        ws[O_CTXT + (long long)j * 32 + b] = a;
      }
    }
    grid.sync();

    // ---- C: av = tanh([ctx|h2] @ attnW^T + b), k-split with last-block finalize ----
    {
      int jc = bid >> 4, kp = bid & 15; // 16 jc(64 j) x 16 kp(128 k)
      int jl = tid & 63, bh = tid >> 6; // bh: 16 groups of 2 b
      int b0 = bh * 2;
      int j = jc * 64 + jl;
      float acc0 = 0, acc1 = 0;
      int kk0 = kp * 128;
      const float* wb = ws + O_ATTNWT + (long long)kk0 * 1024 + j;
      const float* xb = (kk0 < 1024) ? (ws + O_CTXT + (long long)kk0 * 32 + b0)
                                     : (ws + (par ? O_H0 : O_H1) + (long long)(kk0 - 1024) * 32 + b0);
      for (int k = 0; k < 128; ++k) {
        float w = wb[(long long)k * 1024];
        float2 x = *(const float2*)(xb + k * 32);
        acc0 += x.x * w; acc1 += x.y * w;
      }
      ws[O_PAC + ((long long)(kp * 32) + b0) * 1024 + j] = acc0;
      ws[O_PAC + ((long long)(kp * 32) + b0 + 1) * 1024 + j] = acc1;
      __threadfence();
      int* flag = (int*)(smem + 10600);
      if (tid == 0) {
        int old = atomicAdd((int*)(ws + O_CTR) + 8 + jc, 1);
        *flag = (old == 15) ? 1 : 0;
      }
      __syncthreads();
      if (*flag) {
        __threadfence();
        #pragma unroll
        for (int o = 0; o < 2; ++o) {
          int oo = tid + o * 1024;
          int j2 = jc * 64 + (oo >> 5), b = oo & 31;
          float sum = 0;
          #pragma unroll
          for (int kp2 = 0; kp2 < 16; ++kp2)
            sum += ws[O_PAC + ((long long)(kp2 * 32) + b) * 1024 + j2];
          ws[O_AVT + (long long)j2 * 32 + b] = tanhf(sum + attnB[j2]);
        }
        if (tid == 0) atomicSub((int*)(ws + O_CTR) + 8 + jc, 16);
      }
    }
    grid.sync();

    // ---- D: preds = av @ clsW^T + b, write out, block argmax partials ----
    if (bid < 250) {
      float* wc = smem; // [64][128] staged cls weights
      int jl = tid & 127, bg = tid >> 7;
      int b0 = bg * 4;
      int j = bid * 128 + jl;
      float acc[4] = {0,0,0,0};
      for (int kc = 0; kc < 1024; kc += 64) {
        {
          int r = tid >> 7, cc = tid & 127;
          #pragma unroll
          for (int i = 0; i < 8; ++i) {
            int kk = r + (i << 3);
            wc[kk * 128 + cc] = ws[O_CLSWT + (long long)(kc + kk) * 32000 + bid * 128 + cc];
          }
        }
        __syncthreads();
        for (int k = 0; k < 64; ++k) {
          float w = wc[k * 128 + jl];
          float4 a = *(const float4*)(ws + O_AVT + (long long)(kc + k) * 32 + b0);
          acc[0] += a.x * w; acc[1] += a.y * w; acc[2] += a.z * w; acc[3] += a.w * w;
        }
        __syncthreads();
      }
      float cb = clsB[j];
      float pvv[4];
      #pragma unroll
      for (int i = 0; i < 4; ++i) {
        pvv[i] = acc[i] + cb;
        out[((long long)s * 32 + b0 + i) * 32000 + j] = pvv[i];
      }
      // block argmax (first-index on ties)
      float* lv = smem;                 // [32][128]
      int*   li = (int*)(smem + 4096);  // [32][128]
      __syncthreads();
      #pragma unroll
      for (int i = 0; i < 4; ++i) {
        lv[(b0 + i) * 128 + jl] = pvv[i];
        li[(b0 + i) * 128 + jl] = j;
      }
      __syncthreads();
      float* l2v = smem + 8192;         // [32][32]
      int*   l2i = (int*)(smem + 9216); // [32][32]
      {
        int b = tid >> 5, r = tid & 31;
        float bv = -3.4e38f; int bi = 0;
        #pragma unroll
        for (int i = 0; i < 4; ++i) {
          float v = lv[b * 128 + r + (i << 5)];
          int ix = li[b * 128 + r + (i << 5)];
          if (v > bv || (v == bv && ix < bi)) { bv = v; bi = ix; }
        }
        l2v[b * 32 + r] = bv; l2i[b * 32 + r] = bi;
      }
      __syncthreads();
      if (tid < 32) {
        float bv = -3.4e38f; int bi = 0;
        for (int r = 0; r < 32; ++r) {
          float v = l2v[tid * 32 + r]; int ix = l2i[tid * 32 + r];
          if (v > bv || (v == bv && ix < bi)) { bv = v; bi = ix; }
        }
        ws[O_PARGV + bid * 32 + tid] = bv;
        ((int*)(ws + O_PARGI))[bid * 32 + tid] = bi;
      }
    }
    grid.sync();
    par ^= 1;
  }
}

extern "C" void kernel_launch(void* const* d_in, const int* in_sizes, int n_in,
                              void* d_out, int out_size, void* d_ws, size_t ws_size,
                              hipStream_t stream) {
  const int*   inp    = (const int*)  d_in[0];
  const float* encEmb = (const float*)d_in[1];
  const float* encWih = (const float*)d_in[2];
  const float* encWhh = (const float*)d_in[3];
  const float* encBih = (const float*)d_in[4];
  const float* encBhh = (const float*)d_in[5];
  const float* decEmb = (const float*)d_in[6];
  const float* decWih = (const float*)d_in[7];
  const float* decWhh = (const float*)d_in[8];
  const float* decBih = (const float*)d_in[9];
  const float* decBhh = (const float*)d_in[10];
  const float* attnW  = (const float*)d_in[11];
  const float* attnB  = (const float*)d_in[12];
  const float* clsW   = (const float*)d_in[13];
  const float* clsB   = (const float*)d_in[14];
  float* out = (float*)d_out;
  float* ws  = (float*)d_ws;

  if (ws_size < (size_t)WS_FLOATS * sizeof(float)) return; // fail loudly via absmax

  void* args[] = { &inp, &encEmb, &encWih, &encWhh, &encBih, &encBhh,
                   &decEmb, &decWih, &decWhh, &decBih, &decBhh,
                   &attnW, &attnB, &clsW, &clsB, &out, &ws };
  hipLaunchCooperativeKernel((void*)seq2seq_kernel, dim3(NBLK), dim3(NTHR),
                             args, 0, stream);
}